// Round 9
// baseline (357.841 us; speedup 1.0000x reference)
//
#include <hip/hip_runtime.h>
#include <math.h>

#define EPSF 1e-8f
#define LAM 20.0f

typedef short short8 __attribute__((ext_vector_type(8)));
typedef float f32x4 __attribute__((ext_vector_type(4)));

__device__ __forceinline__ unsigned short f2bf(float x) {
  unsigned u = __float_as_uint(x);
  u += 0x7fffu + ((u >> 16) & 1u);
  return (unsigned short)(u >> 16);
}
__device__ __forceinline__ float bf2f(unsigned short h) {
  return __uint_as_float(((unsigned)h) << 16);
}

// ---------------------------------------------------------------------------
// Kernel 1: row norms + bf16 normalized copies (R7-proven).
// ---------------------------------------------------------------------------
__global__ __launch_bounds__(256) void norm_convert(
    const float* __restrict__ im, const float* __restrict__ s,
    float* __restrict__ nim, float* __restrict__ ns,
    unsigned short* __restrict__ imn, unsigned short* __restrict__ sn) {
  int row = blockIdx.x * 4 + (threadIdx.x >> 6);
  int lane = threadIdx.x & 63;
  const float* src;
  unsigned short* dst;
  float* ndst;
  if (row < 8192) {
    src = im + ((size_t)row << 9);
    dst = imn + ((size_t)row << 9);
    ndst = nim + row;
  } else {
    int r = row - 8192;
    src = s + ((size_t)r << 9);
    dst = sn + ((size_t)r << 9);
    ndst = ns + r;
  }
  float4 v0 = ((const float4*)src)[lane * 2];
  float4 v1 = ((const float4*)src)[lane * 2 + 1];
  float ss = 0.f;
  ss = fmaf(v0.x, v0.x, ss); ss = fmaf(v0.y, v0.y, ss);
  ss = fmaf(v0.z, v0.z, ss); ss = fmaf(v0.w, v0.w, ss);
  ss = fmaf(v1.x, v1.x, ss); ss = fmaf(v1.y, v1.y, ss);
  ss = fmaf(v1.z, v1.z, ss); ss = fmaf(v1.w, v1.w, ss);
#pragma unroll
  for (int o = 32; o; o >>= 1) ss += __shfl_xor(ss, o);
  float n = sqrtf(ss);
  if (lane == 0) *ndst = n;
  float ci = 1.0f / (n + EPSF);
  union { unsigned short us[8]; uint4 v; } p;
  p.us[0] = f2bf(v0.x * ci); p.us[1] = f2bf(v0.y * ci);
  p.us[2] = f2bf(v0.z * ci); p.us[3] = f2bf(v0.w * ci);
  p.us[4] = f2bf(v1.x * ci); p.us[5] = f2bf(v1.y * ci);
  p.us[6] = f2bf(v1.z * ci); p.us[7] = f2bf(v1.w * ci);
  ((uint4*)dst)[lane] = p.v;
}

// ---------------------------------------------------------------------------
// Kernel 2: bf16 Gram via MFMA with DIRECT-GLOBAL fragments (no LDS, no
// barriers). Blocks 0..127: images (LS=64); 128..255: captions (LS=32).
// ---------------------------------------------------------------------------
template <int LS>
__device__ __forceinline__ void gram_body(const unsigned short* __restrict__ nbf,
                                          unsigned short* __restrict__ Gbf, int c) {
  constexpr int RW = LS / 32;  // 2 (LS=64) / 1 (LS=32)
  const int t = threadIdx.x;
  const int w = t >> 6, lane = t & 63, m16 = lane & 15, grp = lane >> 4;
  const int rT0 = (w & 1) * RW, cT0 = (w >> 1) * RW;
  const unsigned short* base = nbf + (((size_t)c * LS) << 9);
  f32x4 g[RW][RW];
#pragma unroll
  for (int ri = 0; ri < RW; ri++)
#pragma unroll
    for (int ci = 0; ci < RW; ci++) g[ri][ci] = {0.f, 0.f, 0.f, 0.f};
#pragma unroll 2
  for (int k16 = 0; k16 < 16; k16++) {
    int ko = k16 * 32 + grp * 8;
    short8 a[RW], b[RW];
#pragma unroll
    for (int ri = 0; ri < RW; ri++)
      a[ri] = *(const short8*)(base + (((rT0 + ri) * 16 + m16) << 9) + ko);
#pragma unroll
    for (int ci = 0; ci < RW; ci++)
      b[ci] = *(const short8*)(base + (((cT0 + ci) * 16 + m16) << 9) + ko);
#pragma unroll
    for (int ri = 0; ri < RW; ri++)
#pragma unroll
      for (int ci = 0; ci < RW; ci++)
        g[ri][ci] = __builtin_amdgcn_mfma_f32_16x16x32_bf16(a[ri], b[ci], g[ri][ci], 0, 0, 0);
  }
#pragma unroll
  for (int ri = 0; ri < RW; ri++)
#pragma unroll
    for (int ci = 0; ci < RW; ci++)
#pragma unroll
      for (int r = 0; r < 4; r++) {
        int s = (rT0 + ri) * 16 + grp * 4 + r;
        int sp = (cT0 + ci) * 16 + m16;
        Gbf[(size_t)c * LS * LS + s * LS + sp] = f2bf(g[ri][ci][r]);
      }
}

__global__ __launch_bounds__(256) void gram_all(
    const unsigned short* __restrict__ imn, const unsigned short* __restrict__ sn,
    unsigned short* __restrict__ Gim, unsigned short* __restrict__ Gs) {
  if (blockIdx.x < 128) gram_body<64>(imn, Gim, blockIdx.x);
  else gram_body<32>(sn, Gs, blockIdx.x - 128);
}

// ---------------------------------------------------------------------------
// Kernel 3: macro-tiled fused attention. P1 = 128x128x512 GEMM with
// DIRECT-GLOBAL MFMA fragments: no staging, no P1 barriers (4 barriers total).
// ---------------------------------------------------------------------------
template <int LS, int LQ, int GC, int GQ>
__global__ __launch_bounds__(256, 3) void attn_tile(
    const unsigned short* __restrict__ ctxn,  // (128,LS,512) bf16
    const unsigned short* __restrict__ qryn,  // (128,LQ,512) bf16
    const unsigned short* __restrict__ Gbf,   // (128,LS,LS) bf16
    const float* __restrict__ qnrm,           // 128*LQ raw query norms
    const float* __restrict__ cmask,          // (128,LS)
    float* __restrict__ sim) {
  static_assert(GC * LS == 128 && GQ * LQ == 128, "tile must be 128x128");
  constexpr int S0P = 264;                  // S0/e row pitch (bytes)
  constexpr int FOFF = 127 * S0P + 256;     // 33784
  constexpr int WPC = 4 / GC;               // waves per context in P3
  constexpr int KS3 = LS / 32;              // P3 k-steps: 2 (i2t) / 1 (t2i)
  constexpr int NF = GQ * 128 + 2 * GC * 128 + 512 + 256 + GC;
  __shared__ __align__(16) char sm[FOFF + NF * 4];
  float* rinvv = (float*)(sm + FOFF);       // [GQ][128]
  float* sumev = rinvv + GQ * 128;          // [GC][128]  sum e*v
  float* invv = sumev + GC * 128;           // [GC][128]  1/sum e
  float* psum = invv + GC * 128;            // [4][128] wn2 wave partials
  float* cmv = psum + 512;                  // [128]
  float* qnv = cmv + 128;                   // [128]
  float* cmmaxv = qnv + 128;                // [GC]

  const int bq = blockIdx.x, bc = blockIdx.y, t = threadIdx.x;
  const int w = t >> 6, lane = t & 63, m16 = lane & 15, grp = lane >> 4;

  auto soff = [](int n) { return n * S0P; };

  const unsigned short* aBase = ctxn + ((size_t)bc << 16);  // bc*128*512
  const unsigned short* bBase = qryn + ((size_t)bq << 16);

  // ---- preload cmask, qnorms; G fragments -> registers ----
  if (t < 128) cmv[t] = cmask[bc * 128 + t];
  else qnv[t - 128] = qnrm[bq * 128 + (t - 128)];
  const int c3 = w / WPC, hf = w % WPC;
  short8 g_a[2][KS3];
  {
    const unsigned short* gB = Gbf + (size_t)bc * GC * LS * LS + c3 * LS * LS;
#pragma unroll
    for (int mi = 0; mi < 2; mi++) {
      int sp = (hf * 2 + mi) * 16 + m16;
#pragma unroll
      for (int ks = 0; ks < KS3; ks++)
        g_a[mi][ks] = *(const short8*)(gB + sp * LS + ks * 32 + grp * 8);
    }
  }

  // shared accumulator file: P1 uses regs[si*4+ni], P3 uses regs[mi*8+nt]
  f32x4 regs[16];
#pragma unroll
  for (int i = 0; i < 16; i++) regs[i] = {0.f, 0.f, 0.f, 0.f};

  // ---- Phase 1: direct-global fragment GEMM, 4x4 16-tiles per wave ----
  const int sT0 = (w & 1) * 4, nT0 = (w >> 1) * 4;
  const unsigned short* aRow = aBase + (((sT0 * 16 + m16) << 9));
  const unsigned short* bRow = bBase + (((nT0 * 16 + m16) << 9));
#pragma unroll 2
  for (int k16 = 0; k16 < 16; k16++) {
    int ko = k16 * 32 + grp * 8;
    short8 av[4], bv[4];
#pragma unroll
    for (int si = 0; si < 4; si++)
      av[si] = *(const short8*)(aRow + (si << 13) + ko);
#pragma unroll
    for (int ni = 0; ni < 4; ni++)
      bv[ni] = *(const short8*)(bRow + (ni << 13) + ko);
#pragma unroll
    for (int si = 0; si < 4; si++)
#pragma unroll
      for (int ni = 0; ni < 4; ni++)
        regs[si * 4 + ni] = __builtin_amdgcn_mfma_f32_16x16x32_bf16(
            av[si], bv[ni], regs[si * 4 + ni], 0, 0, 0);
  }
  // write S0 bf16 [n][m]; C-layout rows (grp*4+r) are consecutive m -> 8B store
#pragma unroll
  for (int si = 0; si < 4; si++)
#pragma unroll
    for (int ni = 0; ni < 4; ni++) {
      int n = (nT0 + ni) * 16 + m16;
      int m0 = (sT0 + si) * 16 + grp * 4;
      f32x4 a = regs[si * 4 + ni];
      ushort4 p;
      p.x = f2bf(a[0]); p.y = f2bf(a[1]);
      p.z = f2bf(a[2]); p.w = f2bf(a[3]);
      *(ushort4*)(sm + soff(n) + m0 * 2) = p;
    }
  __syncthreads();

  // ---- Phase 2a: rinv (vectorized b64) + per-ci cmask max ----
  {
    if (t < GQ * 32) {
      int qi = t >> 5, mg = (t & 31) * 4;
      float s0 = 0.f, s1 = 0.f, s2 = 0.f, s3 = 0.f;
      for (int l = 0; l < LQ; l++) {
        uint2 pk = *(const uint2*)(sm + soff(qi * LQ + l) + mg * 2);
        float v0 = __uint_as_float(pk.x << 16);
        float v1 = __uint_as_float(pk.x & 0xffff0000u);
        float v2 = __uint_as_float(pk.y << 16);
        float v3 = __uint_as_float(pk.y & 0xffff0000u);
        v0 = v0 > 0.f ? v0 : 0.1f * v0;
        v1 = v1 > 0.f ? v1 : 0.1f * v1;
        v2 = v2 > 0.f ? v2 : 0.1f * v2;
        v3 = v3 > 0.f ? v3 : 0.1f * v3;
        s0 = fmaf(v0, v0, s0); s1 = fmaf(v1, v1, s1);
        s2 = fmaf(v2, v2, s2); s3 = fmaf(v3, v3, s3);
      }
      rinvv[qi * 128 + mg + 0] = 1.0f / (sqrtf(s0) + EPSF);
      rinvv[qi * 128 + mg + 1] = 1.0f / (sqrtf(s1) + EPSF);
      rinvv[qi * 128 + mg + 2] = 1.0f / (sqrtf(s2) + EPSF);
      rinvv[qi * 128 + mg + 3] = 1.0f / (sqrtf(s3) + EPSF);
    } else if (t < GQ * 32 + GC) {
      int ci = t - GQ * 32;
      float mx = cmv[ci * LS];
      for (int s = 1; s < LS; s++) mx = fmaxf(mx, cmv[ci * LS + s]);
      cmmaxv[ci] = mx;
    }
  }
  __syncthreads();

  // ---- Phase 2b: ONE-pass softmax (analytic max); store unnormalized e ----
  {
    const int n = t & 127;
    const int qi = n / LQ;
    for (int ci = t >> 7; ci < GC; ci += 2) {
      char* rowp = sm + soff(n) + ci * LS * 2;
      const float* rv = rinvv + qi * 128 + ci * LS;
      const float* cv = cmv + ci * LS;
      const float mxc = LAM * (1.0f + cmmaxv[ci]);
      float sum = 0.f, sev = 0.f;
#pragma unroll
      for (int u = 0; u < LS / 4; u++) {
        uint2 pk = *(const uint2*)(rowp + u * 8);
        float v0 = __uint_as_float(pk.x << 16);
        float v1 = __uint_as_float(pk.x & 0xffff0000u);
        float v2 = __uint_as_float(pk.y << 16);
        float v3 = __uint_as_float(pk.y & 0xffff0000u);
        int s = u * 4;
        float l0 = v0 > 0.f ? v0 : 0.1f * v0;
        float l1 = v1 > 0.f ? v1 : 0.1f * v1;
        float l2 = v2 > 0.f ? v2 : 0.1f * v2;
        float l3 = v3 > 0.f ? v3 : 0.1f * v3;
        float e0 = __expf(LAM * fmaf(l0, rv[s + 0], cv[s + 0]) - mxc);
        float e1 = __expf(LAM * fmaf(l1, rv[s + 1], cv[s + 1]) - mxc);
        float e2 = __expf(LAM * fmaf(l2, rv[s + 2], cv[s + 2]) - mxc);
        float e3 = __expf(LAM * fmaf(l3, rv[s + 3], cv[s + 3]) - mxc);
        sum += (e0 + e1) + (e2 + e3);
        sev = fmaf(e0, v0, sev); sev = fmaf(e1, v1, sev);
        sev = fmaf(e2, v2, sev); sev = fmaf(e3, v3, sev);
        uint2 o;
        o.x = (unsigned)f2bf(e0) | ((unsigned)f2bf(e1) << 16);
        o.y = (unsigned)f2bf(e2) | ((unsigned)f2bf(e3) << 16);
        *(uint2*)(rowp + u * 8) = o;
      }
      sumev[ci * 128 + n] = sev;
      invv[ci * 128 + n] = 1.0f / sum;
    }
  }
  __syncthreads();

  // ---- Phase 3: per-c U = G_c @ e_c (MFMA, A from regs); wn2 from C-regs ----
  {
#pragma unroll
    for (int i = 0; i < 16; i++) regs[i] = {0.f, 0.f, 0.f, 0.f};
#pragma unroll
    for (int ks = 0; ks < KS3; ks++) {
      short8 b2[8];
#pragma unroll
      for (int nt = 0; nt < 8; nt++) {
        const char* p = sm + soff(nt * 16 + m16) + c3 * LS * 2 + ks * 64 + grp * 16;
        union { uint2 h[2]; short8 v; } bb;
        bb.h[0] = *(const uint2*)(p);
        bb.h[1] = *(const uint2*)(p + 8);
        b2[nt] = bb.v;
      }
#pragma unroll
      for (int mi = 0; mi < 2; mi++)
#pragma unroll
        for (int nt = 0; nt < 8; nt++)
          regs[mi * 8 + nt] = __builtin_amdgcn_mfma_f32_16x16x32_bf16(
              g_a[mi][ks], b2[nt], regs[mi * 8 + nt], 0, 0, 0);
    }
    float wp[8];
#pragma unroll
    for (int nt = 0; nt < 8; nt++) wp[nt] = 0.f;
#pragma unroll
    for (int nt = 0; nt < 8; nt++) {
#pragma unroll
      for (int mi = 0; mi < 2; mi++) {
        int sp = (hf * 2 + mi) * 16 + grp * 4;
        uint2 ee = *(const uint2*)(sm + soff(nt * 16 + m16) + (c3 * LS + sp) * 2);
        f32x4 uu = regs[mi * 8 + nt];
        wp[nt] += __uint_as_float(ee.x << 16) * uu[0] +
                  __uint_as_float(ee.x & 0xffff0000u) * uu[1] +
                  __uint_as_float(ee.y << 16) * uu[2] +
                  __uint_as_float(ee.y & 0xffff0000u) * uu[3];
      }
    }
#pragma unroll
    for (int o = 16; o < 64; o <<= 1)
#pragma unroll
      for (int nt = 0; nt < 8; nt++) wp[nt] += __shfl_xor(wp[nt], o);
    if (lane < 16) {
#pragma unroll
      for (int nt = 0; nt < 8; nt++) psum[w * 128 + nt * 16 + lane] = wp[nt];
    }
  }
  __syncthreads();

  // ---- Final: cos + mean over l -> sim ----
  {
    const int p = t >> 5, l0 = t & 31;
    const int cc = p / GQ, qi = p % GQ;
    float sum = 0.f;
#pragma unroll
    for (int li = 0; li < LQ / 32; li++) {
      int n = qi * LQ + l0 + li * 32;
      float nq = qnv[n];
      float inv = invv[cc * 128 + n];
      float w12 = sumev[cc * 128 + n] * inv;
      float wn2u = 0.f;
#pragma unroll
      for (int h = 0; h < WPC; h++) wn2u += psum[(cc * WPC + h) * 128 + n];
      float wn2 = wn2u * inv * inv;
      float denom = fmaxf(nq * sqrtf(fmaxf(wn2, 0.f)), 1e-8f);
      sum += (nq + EPSF) * w12 / denom;
    }
#pragma unroll
    for (int o = 1; o < 32; o <<= 1) sum += __shfl_xor(sum, o);
    if (l0 == 0) sim[(bc * GC + cc) * 128 + bq * GQ + qi] = sum * (1.0f / (float)LQ);
  }
}

// ---------------------------------------------------------------------------
// Loss reductions (unchanged, exact).
// ---------------------------------------------------------------------------
__global__ __launch_bounds__(128) void loss_rows(
    const float* __restrict__ gsim, const float* __restrict__ i2t,
    const float* __restrict__ t2i, float* __restrict__ grow,
    float* __restrict__ gcol, float* __restrict__ lrow) {
  const int i = blockIdx.x, j = threadIdx.x;
  const int B = 128;
  __shared__ float sh[2];
  auto bmax = [&](float v) -> float {
#pragma unroll
    for (int o = 32; o; o >>= 1) v = fmaxf(v, __shfl_down(v, o));
    if ((j & 63) == 0) sh[j >> 6] = v;
    __syncthreads();
    float r = fmaxf(sh[0], sh[1]);
    __syncthreads();
    return r;
  };
  auto bsum = [&](float v) -> float {
#pragma unroll
    for (int o = 32; o; o >>= 1) v += __shfl_down(v, o);
    if ((j & 63) == 0) sh[j >> 6] = v;
    __syncthreads();
    float r = sh[0] + sh[1];
    __syncthreads();
    return r;
  };
  float xr = gsim[i * B + j] * 20.f;
  float xc = gsim[j * B + i] * 20.f;
  float sc = (i2t[i * B + j] + t2i[j * B + i]) * LAM;
  float mr = bmax(xr);
  float lser = mr + logf(bsum(__expf(xr - mr)));
  float mc = bmax(xc);
  float lsec = mc + logf(bsum(__expf(xc - mc)));
  float ml = bmax(sc);
  float lsel = ml + logf(bsum(__expf(sc - ml)));
  float pred = __expf(sc - lsel);
  float logLab = (i == j) ? logf(1.0f + 1e-6f) : logf(1e-6f);
  float tsum = bsum(pred * (sc - lsel - logLab));
  if (j == 0) {
    float d = gsim[i * B + i] * 20.f;
    grow[i] = d - lser;
    gcol[i] = d - lsec;
    lrow[i] = tsum;
  }
}

__global__ __launch_bounds__(128) void loss_final(const float* __restrict__ grow,
                                                  const float* __restrict__ gcol,
                                                  const float* __restrict__ lrow,
                                                  float* __restrict__ out) {
  const int j = threadIdx.x;
  __shared__ float sh[2];
  auto bsum = [&](float v) -> float {
#pragma unroll
    for (int o = 32; o; o >>= 1) v += __shfl_down(v, o);
    if ((j & 63) == 0) sh[j >> 6] = v;
    __syncthreads();
    float r = sh[0] + sh[1];
    __syncthreads();
    return r;
  };
  float a = bsum(grow[j]);
  float b = bsum(gcol[j]);
  float c = bsum(lrow[j]);
  if (j == 0) {
    float gl = -(a / 128.f) - (b / 128.f);
    float ll = c / 128.f;
    out[0] = gl + ll;
    out[1] = gl;
    out[2] = ll;
  }
}

extern "C" void kernel_launch(void* const* d_in, const int* in_sizes, int n_in,
                              void* d_out, int out_size, void* d_ws,
                              size_t ws_size, hipStream_t stream) {
  const float* gsim = (const float*)d_in[0];  // (128,128)
  const float* im = (const float*)d_in[1];    // (128,64,512)
  const float* s = (const float*)d_in[2];     // (128,32,512)
  const float* im_m = (const float*)d_in[3];  // (128,64)
  const float* s_m = (const float*)d_in[5];   // (128,32)
  float* out = (float*)d_out;

  float* ws = (float*)d_ws;
  float* nim = ws;                                         // 8192
  float* ns = ws + 8192;                                   // 4096
  float* i2t = ws + 12288;                                 // 16384
  float* t2i = ws + 28672;                                 // 16384
  float* grow = ws + 45056;                                // 128
  float* gcol = ws + 45184;                                // 128
  float* lrow = ws + 45312;                                // 128
  unsigned short* Gim = (unsigned short*)(ws + 45440);     // 128*64*64 bf16
  unsigned short* Gs = (unsigned short*)(ws + 307584);     // 128*32*32 bf16
  unsigned short* imn = (unsigned short*)(ws + 373120);    // 128*64*512 bf16
  unsigned short* sn = (unsigned short*)(ws + 2470272);    // 128*32*512 bf16

  norm_convert<<<dim3(3072), dim3(256), 0, stream>>>(im, s, nim, ns, imn, sn);
  gram_all<<<dim3(256), dim3(256), 0, stream>>>(imn, sn, Gim, Gs);
  // i2t: ctx=images(LS=64,GC=2), qry=captions(LQ=32,GQ=4)
  attn_tile<64, 32, 2, 4><<<dim3(32, 64), dim3(256), 0, stream>>>(
      imn, sn, Gim, ns, im_m, i2t);
  // t2i: ctx=captions(LS=32,GC=4), qry=images(LQ=64,GQ=2)
  attn_tile<32, 64, 4, 2><<<dim3(64, 32), dim3(256), 0, stream>>>(
      sn, imn, Gs, nim, s_m, t2i);
  loss_rows<<<dim3(128), dim3(128), 0, stream>>>(gsim, i2t, t2i, grow, gcol, lrow);
  loss_final<<<dim3(1), dim3(128), 0, stream>>>(grow, gcol, lrow, out);
}

// Round 10
// 258.559 us; speedup vs baseline: 1.3840x; 1.3840x over previous
//
#include <hip/hip_runtime.h>
#include <math.h>

#define EPSF 1e-8f
#define LAM 20.0f

typedef short short8 __attribute__((ext_vector_type(8)));
typedef float f32x4 __attribute__((ext_vector_type(4)));

__device__ __forceinline__ unsigned short f2bf(float x) {
  unsigned u = __float_as_uint(x);
  u += 0x7fffu + ((u >> 16) & 1u);
  return (unsigned short)(u >> 16);
}
__device__ __forceinline__ float bf2f(unsigned short h) {
  return __uint_as_float(((unsigned)h) << 16);
}

// ---------------------------------------------------------------------------
// Kernel 1: row norms + bf16 normalized copies (R7-proven).
// ---------------------------------------------------------------------------
__global__ __launch_bounds__(256) void norm_convert(
    const float* __restrict__ im, const float* __restrict__ s,
    float* __restrict__ nim, float* __restrict__ ns,
    unsigned short* __restrict__ imn, unsigned short* __restrict__ sn) {
  int row = blockIdx.x * 4 + (threadIdx.x >> 6);
  int lane = threadIdx.x & 63;
  const float* src;
  unsigned short* dst;
  float* ndst;
  if (row < 8192) {
    src = im + ((size_t)row << 9);
    dst = imn + ((size_t)row << 9);
    ndst = nim + row;
  } else {
    int r = row - 8192;
    src = s + ((size_t)r << 9);
    dst = sn + ((size_t)r << 9);
    ndst = ns + r;
  }
  float4 v0 = ((const float4*)src)[lane * 2];
  float4 v1 = ((const float4*)src)[lane * 2 + 1];
  float ss = 0.f;
  ss = fmaf(v0.x, v0.x, ss); ss = fmaf(v0.y, v0.y, ss);
  ss = fmaf(v0.z, v0.z, ss); ss = fmaf(v0.w, v0.w, ss);
  ss = fmaf(v1.x, v1.x, ss); ss = fmaf(v1.y, v1.y, ss);
  ss = fmaf(v1.z, v1.z, ss); ss = fmaf(v1.w, v1.w, ss);
#pragma unroll
  for (int o = 32; o; o >>= 1) ss += __shfl_xor(ss, o);
  float n = sqrtf(ss);
  if (lane == 0) *ndst = n;
  float ci = 1.0f / (n + EPSF);
  union { unsigned short us[8]; uint4 v; } p;
  p.us[0] = f2bf(v0.x * ci); p.us[1] = f2bf(v0.y * ci);
  p.us[2] = f2bf(v0.z * ci); p.us[3] = f2bf(v0.w * ci);
  p.us[4] = f2bf(v1.x * ci); p.us[5] = f2bf(v1.y * ci);
  p.us[6] = f2bf(v1.z * ci); p.us[7] = f2bf(v1.w * ci);
  ((uint4*)dst)[lane] = p.v;
}

// ---------------------------------------------------------------------------
// Kernel 2: bf16 Gram matrices via MFMA (R7 LDS-staged bodies), one launch.
// Blocks 0..127: images (LS=64). Blocks 128..255: captions (LS=32).
// ---------------------------------------------------------------------------
template <int LS>
__device__ __forceinline__ void gram_body(const unsigned short* __restrict__ ctxn,
                                          unsigned short* __restrict__ Gbf,
                                          int c, char* sm) {
  constexpr int RW = (LS / 16) / 2;
  const int t = threadIdx.x;
  const int w = t >> 6, lane = t & 63, m16 = lane & 15, grp = lane >> 4;
  const int rT0 = (w & 1) * RW, cT0 = (w >> 1) * RW;
  const unsigned short* base = ctxn + ((size_t)c * LS << 9);
  f32x4 g[RW][RW];
#pragma unroll
  for (int ri = 0; ri < RW; ri++)
#pragma unroll
    for (int ci = 0; ci < RW; ci++) g[ri][ci] = {0.f, 0.f, 0.f, 0.f};

  for (int ch = 0; ch < 4; ch++) {
    __syncthreads();
    for (int idx = t; idx < LS * 16; idx += 256) {
      int row = idx >> 4, u = idx & 15;
      *(uint4*)(sm + row * 272 + u * 16) =
          ((const uint4*)(base + ((size_t)row << 9) + (ch << 7)))[u];
    }
    __syncthreads();
#pragma unroll
    for (int kk = 0; kk < 4; kk++) {
      short8 a[RW], b[RW];
#pragma unroll
      for (int ri = 0; ri < RW; ri++)
        a[ri] = *(const short8*)(sm + ((rT0 + ri) * 16 + m16) * 272 + kk * 64 + grp * 16);
#pragma unroll
      for (int ci = 0; ci < RW; ci++)
        b[ci] = *(const short8*)(sm + ((cT0 + ci) * 16 + m16) * 272 + kk * 64 + grp * 16);
#pragma unroll
      for (int ri = 0; ri < RW; ri++)
#pragma unroll
        for (int ci = 0; ci < RW; ci++)
          g[ri][ci] = __builtin_amdgcn_mfma_f32_16x16x32_bf16(a[ri], b[ci], g[ri][ci], 0, 0, 0);
    }
  }
#pragma unroll
  for (int ri = 0; ri < RW; ri++)
#pragma unroll
    for (int ci = 0; ci < RW; ci++)
#pragma unroll
      for (int r = 0; r < 4; r++) {
        int s = (rT0 + ri) * 16 + grp * 4 + r;
        int sp = (cT0 + ci) * 16 + m16;
        Gbf[(size_t)c * LS * LS + s * LS + sp] = f2bf(g[ri][ci][r]);
      }
}

__global__ __launch_bounds__(256, 2) void gram_all(
    const unsigned short* __restrict__ imn, const unsigned short* __restrict__ sn,
    unsigned short* __restrict__ Gim, unsigned short* __restrict__ Gs) {
  __shared__ __align__(16) char sm[64 * 272];
  if (blockIdx.x < 128) gram_body<64>(imn, Gim, blockIdx.x, sm);
  else gram_body<32>(sn, Gs, blockIdx.x - 128, sm);
}

// ---------------------------------------------------------------------------
// Kernel 3: fused dual-direction macro-tiled attention (R7 body).
// Flat grid 4096: blocks 0..2047 = i2t <64,32,2,4>, 2048..4095 = t2i <32,64,4,2>.
// ---------------------------------------------------------------------------
template <int LS, int LQ, int GC, int GQ>
__device__ __forceinline__ void attn_body(
    char* __restrict__ sm, int bq, int bc,
    const unsigned short* __restrict__ ctxn,  // (128,LS,512) bf16
    const unsigned short* __restrict__ qryn,  // (128,LQ,512) bf16
    const unsigned short* __restrict__ Gbf,   // (128,LS,LS) bf16
    const float* __restrict__ qnrm,           // 128*LQ raw query norms
    const float* __restrict__ cmask,          // (128,LS)
    float* __restrict__ sim) {
  static_assert(GC * LS == 128 && GQ * LQ == 128, "tile must be 128x128");
  constexpr int SROW = 144;                 // staging row stride (64 bf16 + pad)
  constexpr int S0P = 264;                  // S0/e row pitch (bytes)
  constexpr int FOFF = 127 * S0P + 256;     // 33784: union(staging 36864->fits? no:
  // NOTE: staging needs 256*144=36864 > FOFF. Place staging at 0 with S0 after?
  // R7 layout: staging 256*SROW=36864 and S0 (33784) alias the SAME region,
  // float scratch after max(36864, 33784) = 36864.
  constexpr int SCR = 256 * SROW;           // 36864 float scratch offset
  constexpr int WPC = 4 / GC;               // waves per context in P3
  constexpr int KS3 = LS / 32;              // P3 k-steps: 2 (i2t) / 1 (t2i)
  float* rinvv = (float*)(sm + SCR);        // [GQ][128]
  float* sumev = rinvv + GQ * 128;          // [GC][128]  sum e*v
  float* invv = sumev + GC * 128;           // [GC][128]  1/sum e
  float* psum = invv + GC * 128;            // [4][128] wn2 wave partials
  float* cmv = psum + 512;                  // [128]
  float* qnv = cmv + 128;                   // [128]
  float* cmmaxv = qnv + 128;                // [GC]

  const int t = threadIdx.x;
  const int w = t >> 6, lane = t & 63, m16 = lane & 15, grp = lane >> 4;

  auto soff = [](int n) { return n * S0P; };

  const unsigned short* aBase = ctxn + ((size_t)bc << 16);  // bc*128*512
  const unsigned short* bBase = qryn + ((size_t)bq << 16);

  // ---- preload cmask, qnorms; G fragments -> registers ----
  if (t < 128) cmv[t] = cmask[bc * 128 + t];
  else qnv[t - 128] = qnrm[bq * 128 + (t - 128)];
  const int c3 = w / WPC, hf = w % WPC;
  short8 g_a[2][KS3];
  {
    const unsigned short* gB = Gbf + (size_t)bc * GC * LS * LS + c3 * LS * LS;
#pragma unroll
    for (int mi = 0; mi < 2; mi++) {
      int sp = (hf * 2 + mi) * 16 + m16;
#pragma unroll
      for (int ks = 0; ks < KS3; ks++)
        g_a[mi][ks] = *(const short8*)(gB + sp * LS + ks * 32 + grp * 8);
    }
  }

  // hoisted staging pointers (row select constant across ch)
  const unsigned short* srcp[8];
  int ldso[8];
#pragma unroll
  for (int i = 0; i < 8; i++) {
    int idx = t + i * 256;
    int row = idx >> 3, u = idx & 7;
    srcp[i] = ((row < 128) ? (aBase + ((size_t)row << 9))
                           : (bBase + ((size_t)(row - 128) << 9))) + u * 8;
    ldso[i] = row * SROW + u * 16;
  }

  // shared accumulator file: P1 uses regs[si*4+ni], P3 uses regs[mi*8+nt]
  f32x4 regs[16];
#pragma unroll
  for (int i = 0; i < 16; i++) regs[i] = {0.f, 0.f, 0.f, 0.f};

  // ---- Phase 1: 128x128x512 score GEMM, 4x4 16-tiles per wave ----
  const int sT0 = (w & 1) * 4, nT0 = (w >> 1) * 4;
  for (int ch = 0; ch < 8; ch++) {
    __syncthreads();  // prior MFMA reads done
#pragma unroll
    for (int i = 0; i < 8; i++)
      *(uint4*)(sm + ldso[i]) = *(const uint4*)(srcp[i] + (ch << 6));
    __syncthreads();  // staging ready
#pragma unroll
    for (int kk = 0; kk < 2; kk++) {
      short8 av[4], bv[4];
#pragma unroll
      for (int si = 0; si < 4; si++)
        av[si] = *(const short8*)(sm + ((sT0 + si) * 16 + m16) * SROW + kk * 64 + grp * 16);
#pragma unroll
      for (int ni = 0; ni < 4; ni++)
        bv[ni] = *(const short8*)(sm + (128 + (nT0 + ni) * 16 + m16) * SROW + kk * 64 + grp * 16);
#pragma unroll
      for (int si = 0; si < 4; si++)
#pragma unroll
        for (int ni = 0; ni < 4; ni++)
          regs[si * 4 + ni] = __builtin_amdgcn_mfma_f32_16x16x32_bf16(
              av[si], bv[ni], regs[si * 4 + ni], 0, 0, 0);
    }
  }
  __syncthreads();
  // write S0 bf16 [n][m]; C-layout rows (grp*4+r) are consecutive m -> 8B store
#pragma unroll
  for (int si = 0; si < 4; si++)
#pragma unroll
    for (int ni = 0; ni < 4; ni++) {
      int n = (nT0 + ni) * 16 + m16;
      int m0 = (sT0 + si) * 16 + grp * 4;
      f32x4 a = regs[si * 4 + ni];
      ushort4 p;
      p.x = f2bf(a[0]); p.y = f2bf(a[1]);
      p.z = f2bf(a[2]); p.w = f2bf(a[3]);
      *(ushort4*)(sm + soff(n) + m0 * 2) = p;
    }
  __syncthreads();

  // ---- Phase 2a: rinv (vectorized b64) + per-ci cmask max ----
  {
    if (t < GQ * 32) {
      int qi = t >> 5, mg = (t & 31) * 4;
      float s0 = 0.f, s1 = 0.f, s2 = 0.f, s3 = 0.f;
      for (int l = 0; l < LQ; l++) {
        uint2 pk = *(const uint2*)(sm + soff(qi * LQ + l) + mg * 2);
        float v0 = __uint_as_float(pk.x << 16);
        float v1 = __uint_as_float(pk.x & 0xffff0000u);
        float v2 = __uint_as_float(pk.y << 16);
        float v3 = __uint_as_float(pk.y & 0xffff0000u);
        v0 = v0 > 0.f ? v0 : 0.1f * v0;
        v1 = v1 > 0.f ? v1 : 0.1f * v1;
        v2 = v2 > 0.f ? v2 : 0.1f * v2;
        v3 = v3 > 0.f ? v3 : 0.1f * v3;
        s0 = fmaf(v0, v0, s0); s1 = fmaf(v1, v1, s1);
        s2 = fmaf(v2, v2, s2); s3 = fmaf(v3, v3, s3);
      }
      rinvv[qi * 128 + mg + 0] = 1.0f / (sqrtf(s0) + EPSF);
      rinvv[qi * 128 + mg + 1] = 1.0f / (sqrtf(s1) + EPSF);
      rinvv[qi * 128 + mg + 2] = 1.0f / (sqrtf(s2) + EPSF);
      rinvv[qi * 128 + mg + 3] = 1.0f / (sqrtf(s3) + EPSF);
    } else if (t < GQ * 32 + GC) {
      int ci = t - GQ * 32;
      float mx = cmv[ci * LS];
      for (int s = 1; s < LS; s++) mx = fmaxf(mx, cmv[ci * LS + s]);
      cmmaxv[ci] = mx;
    }
  }
  __syncthreads();

  // ---- Phase 2b: ONE-pass softmax (analytic max); store unnormalized e ----
  {
    const int n = t & 127;
    const int qi = n / LQ;
    for (int ci = t >> 7; ci < GC; ci += 2) {
      char* rowp = sm + soff(n) + ci * LS * 2;
      const float* rv = rinvv + qi * 128 + ci * LS;
      const float* cv = cmv + ci * LS;
      const float mxc = LAM * (1.0f + cmmaxv[ci]);
      float sum = 0.f, sev = 0.f;
#pragma unroll
      for (int u = 0; u < LS / 4; u++) {
        uint2 pk = *(const uint2*)(rowp + u * 8);
        float v0 = __uint_as_float(pk.x << 16);
        float v1 = __uint_as_float(pk.x & 0xffff0000u);
        float v2 = __uint_as_float(pk.y << 16);
        float v3 = __uint_as_float(pk.y & 0xffff0000u);
        int s = u * 4;
        float l0 = v0 > 0.f ? v0 : 0.1f * v0;
        float l1 = v1 > 0.f ? v1 : 0.1f * v1;
        float l2 = v2 > 0.f ? v2 : 0.1f * v2;
        float l3 = v3 > 0.f ? v3 : 0.1f * v3;
        float e0 = __expf(LAM * fmaf(l0, rv[s + 0], cv[s + 0]) - mxc);
        float e1 = __expf(LAM * fmaf(l1, rv[s + 1], cv[s + 1]) - mxc);
        float e2 = __expf(LAM * fmaf(l2, rv[s + 2], cv[s + 2]) - mxc);
        float e3 = __expf(LAM * fmaf(l3, rv[s + 3], cv[s + 3]) - mxc);
        sum += (e0 + e1) + (e2 + e3);
        sev = fmaf(e0, v0, sev); sev = fmaf(e1, v1, sev);
        sev = fmaf(e2, v2, sev); sev = fmaf(e3, v3, sev);
        uint2 o;
        o.x = (unsigned)f2bf(e0) | ((unsigned)f2bf(e1) << 16);
        o.y = (unsigned)f2bf(e2) | ((unsigned)f2bf(e3) << 16);
        *(uint2*)(rowp + u * 8) = o;
      }
      sumev[ci * 128 + n] = sev;
      invv[ci * 128 + n] = 1.0f / sum;
    }
  }
  __syncthreads();

  // ---- Phase 3: per-c U = G_c @ e_c (MFMA, A from regs); wn2 from C-regs ----
  {
#pragma unroll
    for (int i = 0; i < 16; i++) regs[i] = {0.f, 0.f, 0.f, 0.f};
#pragma unroll
    for (int ks = 0; ks < KS3; ks++) {
      short8 b2[8];
#pragma unroll
      for (int nt = 0; nt < 8; nt++) {
        const char* p = sm + soff(nt * 16 + m16) + c3 * LS * 2 + ks * 64 + grp * 16;
        union { uint2 h[2]; short8 v; } bb;
        bb.h[0] = *(const uint2*)(p);
        bb.h[1] = *(const uint2*)(p + 8);
        b2[nt] = bb.v;
      }
#pragma unroll
      for (int mi = 0; mi < 2; mi++)
#pragma unroll
        for (int nt = 0; nt < 8; nt++)
          regs[mi * 8 + nt] = __builtin_amdgcn_mfma_f32_16x16x32_bf16(
              g_a[mi][ks], b2[nt], regs[mi * 8 + nt], 0, 0, 0);
    }
    float wp[8];
#pragma unroll
    for (int nt = 0; nt < 8; nt++) wp[nt] = 0.f;
#pragma unroll
    for (int nt = 0; nt < 8; nt++) {
#pragma unroll
      for (int mi = 0; mi < 2; mi++) {
        int sp = (hf * 2 + mi) * 16 + grp * 4;
        uint2 ee = *(const uint2*)(sm + soff(nt * 16 + m16) + (c3 * LS + sp) * 2);
        f32x4 uu = regs[mi * 8 + nt];
        wp[nt] += __uint_as_float(ee.x << 16) * uu[0] +
                  __uint_as_float(ee.x & 0xffff0000u) * uu[1] +
                  __uint_as_float(ee.y << 16) * uu[2] +
                  __uint_as_float(ee.y & 0xffff0000u) * uu[3];
      }
    }
#pragma unroll
    for (int o = 16; o < 64; o <<= 1)
#pragma unroll
      for (int nt = 0; nt < 8; nt++) wp[nt] += __shfl_xor(wp[nt], o);
    if (lane < 16) {
#pragma unroll
      for (int nt = 0; nt < 8; nt++) psum[w * 128 + nt * 16 + lane] = wp[nt];
    }
  }
  __syncthreads();

  // ---- Final: cos + mean over l -> sim ----
  {
    const int p = t >> 5, l0 = t & 31;
    const int cc = p / GQ, qi = p % GQ;
    float sum = 0.f;
#pragma unroll
    for (int li = 0; li < LQ / 32; li++) {
      int n = qi * LQ + l0 + li * 32;
      float nq = qnv[n];
      float inv = invv[cc * 128 + n];
      float w12 = sumev[cc * 128 + n] * inv;
      float wn2u = 0.f;
#pragma unroll
      for (int h = 0; h < WPC; h++) wn2u += psum[(cc * WPC + h) * 128 + n];
      float wn2 = wn2u * inv * inv;
      float denom = fmaxf(nq * sqrtf(fmaxf(wn2, 0.f)), 1e-8f);
      sum += (nq + EPSF) * w12 / denom;
    }
#pragma unroll
    for (int o = 1; o < 32; o <<= 1) sum += __shfl_xor(sum, o);
    if (l0 == 0) sim[(bc * GC + cc) * 128 + bq * GQ + qi] = sum * (1.0f / (float)LQ);
  }
}

__global__ __launch_bounds__(256, 3) void attn_both(
    const unsigned short* __restrict__ imn, const unsigned short* __restrict__ sn,
    const unsigned short* __restrict__ Gim, const unsigned short* __restrict__ Gs,
    const float* __restrict__ nim, const float* __restrict__ ns,
    const float* __restrict__ im_m, const float* __restrict__ s_m,
    float* __restrict__ i2t, float* __restrict__ t2i) {
  // max LDS: staging 36864 + t2i float scratch (2052 floats) = 45072 -> pad
  __shared__ __align__(16) char sm[45184];
  const int bid = blockIdx.x;
  if (bid < 2048) {
    attn_body<64, 32, 2, 4>(sm, bid & 31, bid >> 5, imn, sn, Gim, ns, im_m, i2t);
  } else {
    int b = bid - 2048;
    attn_body<32, 64, 4, 2>(sm, b & 63, b >> 6, sn, imn, Gs, nim, s_m, t2i);
  }
}

// ---------------------------------------------------------------------------
// Loss reductions (unchanged, exact).
// ---------------------------------------------------------------------------
__global__ __launch_bounds__(128) void loss_rows(
    const float* __restrict__ gsim, const float* __restrict__ i2t,
    const float* __restrict__ t2i, float* __restrict__ grow,
    float* __restrict__ gcol, float* __restrict__ lrow) {
  const int i = blockIdx.x, j = threadIdx.x;
  const int B = 128;
  __shared__ float sh[2];
  auto bmax = [&](float v) -> float {
#pragma unroll
    for (int o = 32; o; o >>= 1) v = fmaxf(v, __shfl_down(v, o));
    if ((j & 63) == 0) sh[j >> 6] = v;
    __syncthreads();
    float r = fmaxf(sh[0], sh[1]);
    __syncthreads();
    return r;
  };
  auto bsum = [&](float v) -> float {
#pragma unroll
    for (int o = 32; o; o >>= 1) v += __shfl_down(v, o);
    if ((j & 63) == 0) sh[j >> 6] = v;
    __syncthreads();
    float r = sh[0] + sh[1];
    __syncthreads();
    return r;
  };
  float xr = gsim[i * B + j] * 20.f;
  float xc = gsim[j * B + i] * 20.f;
  float sc = (i2t[i * B + j] + t2i[j * B + i]) * LAM;
  float mr = bmax(xr);
  float lser = mr + logf(bsum(__expf(xr - mr)));
  float mc = bmax(xc);
  float lsec = mc + logf(bsum(__expf(xc - mc)));
  float ml = bmax(sc);
  float lsel = ml + logf(bsum(__expf(sc - ml)));
  float pred = __expf(sc - lsel);
  float logLab = (i == j) ? logf(1.0f + 1e-6f) : logf(1e-6f);
  float tsum = bsum(pred * (sc - lsel - logLab));
  if (j == 0) {
    float d = gsim[i * B + i] * 20.f;
    grow[i] = d - lser;
    gcol[i] = d - lsec;
    lrow[i] = tsum;
  }
}

__global__ __launch_bounds__(128) void loss_final(const float* __restrict__ grow,
                                                  const float* __restrict__ gcol,
                                                  const float* __restrict__ lrow,
                                                  float* __restrict__ out) {
  const int j = threadIdx.x;
  __shared__ float sh[2];
  auto bsum = [&](float v) -> float {
#pragma unroll
    for (int o = 32; o; o >>= 1) v += __shfl_down(v, o);
    if ((j & 63) == 0) sh[j >> 6] = v;
    __syncthreads();
    float r = sh[0] + sh[1];
    __syncthreads();
    return r;
  };
  float a = bsum(grow[j]);
  float b = bsum(gcol[j]);
  float c = bsum(lrow[j]);
  if (j == 0) {
    float gl = -(a / 128.f) - (b / 128.f);
    float ll = c / 128.f;
    out[0] = gl + ll;
    out[1] = gl;
    out[2] = ll;
  }
}

extern "C" void kernel_launch(void* const* d_in, const int* in_sizes, int n_in,
                              void* d_out, int out_size, void* d_ws,
                              size_t ws_size, hipStream_t stream) {
  const float* gsim = (const float*)d_in[0];  // (128,128)
  const float* im = (const float*)d_in[1];    // (128,64,512)
  const float* s = (const float*)d_in[2];     // (128,32,512)
  const float* im_m = (const float*)d_in[3];  // (128,64)
  const float* s_m = (const float*)d_in[5];   // (128,32)
  float* out = (float*)d_out;

  float* ws = (float*)d_ws;
  float* nim = ws;                                         // 8192
  float* ns = ws + 8192;                                   // 4096
  float* i2t = ws + 12288;                                 // 16384
  float* t2i = ws + 28672;                                 // 16384
  float* grow = ws + 45056;                                // 128
  float* gcol = ws + 45184;                                // 128
  float* lrow = ws + 45312;                                // 128
  unsigned short* Gim = (unsigned short*)(ws + 45440);     // 128*64*64 bf16
  unsigned short* Gs = (unsigned short*)(ws + 307584);     // 128*32*32 bf16
  unsigned short* imn = (unsigned short*)(ws + 373120);    // 128*64*512 bf16
  unsigned short* sn = (unsigned short*)(ws + 2470272);    // 128*32*512 bf16

  norm_convert<<<dim3(3072), dim3(256), 0, stream>>>(im, s, nim, ns, imn, sn);
  gram_all<<<dim3(256), dim3(256), 0, stream>>>(imn, sn, Gim, Gs);
  attn_both<<<dim3(4096), dim3(256), 0, stream>>>(imn, sn, Gim, Gs, nim, ns,
                                                  im_m, s_m, i2t, t2i);
  loss_rows<<<dim3(128), dim3(128), 0, stream>>>(gsim, i2t, t2i, grow, gcol, lrow);
  loss_final<<<dim3(1), dim3(128), 0, stream>>>(grow, gcol, lrow, out);
}

// Round 11
// 227.602 us; speedup vs baseline: 1.5722x; 1.1360x over previous
//
#include <hip/hip_runtime.h>
#include <math.h>

#define EPSF 1e-8f
#define LAM 20.0f

typedef short short8 __attribute__((ext_vector_type(8)));
typedef float f32x4 __attribute__((ext_vector_type(4)));

__device__ __forceinline__ unsigned short f2bf(float x) {
  unsigned u = __float_as_uint(x);
  u += 0x7fffu + ((u >> 16) & 1u);
  return (unsigned short)(u >> 16);
}
__device__ __forceinline__ float bf2f(unsigned short h) {
  return __uint_as_float(((unsigned)h) << 16);
}

// ---------------------------------------------------------------------------
// Kernel 1: row norms + bf16 normalized copies (K6-proven).
// ---------------------------------------------------------------------------
__global__ __launch_bounds__(256) void norm_convert(
    const float* __restrict__ im, const float* __restrict__ s,
    float* __restrict__ nim, float* __restrict__ ns,
    unsigned short* __restrict__ imn, unsigned short* __restrict__ sn) {
  int row = blockIdx.x * 4 + (threadIdx.x >> 6);
  int lane = threadIdx.x & 63;
  const float* src;
  unsigned short* dst;
  float* ndst;
  if (row < 8192) {
    src = im + ((size_t)row << 9);
    dst = imn + ((size_t)row << 9);
    ndst = nim + row;
  } else {
    int r = row - 8192;
    src = s + ((size_t)r << 9);
    dst = sn + ((size_t)r << 9);
    ndst = ns + r;
  }
  float4 v0 = ((const float4*)src)[lane * 2];
  float4 v1 = ((const float4*)src)[lane * 2 + 1];
  float ss = 0.f;
  ss = fmaf(v0.x, v0.x, ss); ss = fmaf(v0.y, v0.y, ss);
  ss = fmaf(v0.z, v0.z, ss); ss = fmaf(v0.w, v0.w, ss);
  ss = fmaf(v1.x, v1.x, ss); ss = fmaf(v1.y, v1.y, ss);
  ss = fmaf(v1.z, v1.z, ss); ss = fmaf(v1.w, v1.w, ss);
#pragma unroll
  for (int o = 32; o; o >>= 1) ss += __shfl_xor(ss, o);
  float n = sqrtf(ss);
  if (lane == 0) *ndst = n;
  float ci = 1.0f / (n + EPSF);
  union { unsigned short us[8]; uint4 v; } p;
  p.us[0] = f2bf(v0.x * ci); p.us[1] = f2bf(v0.y * ci);
  p.us[2] = f2bf(v0.z * ci); p.us[3] = f2bf(v0.w * ci);
  p.us[4] = f2bf(v1.x * ci); p.us[5] = f2bf(v1.y * ci);
  p.us[6] = f2bf(v1.z * ci); p.us[7] = f2bf(v1.w * ci);
  ((uint4*)dst)[lane] = p.v;
}

// ---------------------------------------------------------------------------
// Kernel 2: bf16 Gram matrices via MFMA (LDS-staged bodies), one launch.
// Blocks 0..127: images (LS=64). Blocks 128..255: captions (LS=32).
// ---------------------------------------------------------------------------
template <int LS>
__device__ __forceinline__ void gram_body(const unsigned short* __restrict__ ctxn,
                                          unsigned short* __restrict__ Gbf,
                                          int c, char* sm) {
  constexpr int RW = (LS / 16) / 2;
  const int t = threadIdx.x;
  const int w = t >> 6, lane = t & 63, m16 = lane & 15, grp = lane >> 4;
  const int rT0 = (w & 1) * RW, cT0 = (w >> 1) * RW;
  const unsigned short* base = ctxn + ((size_t)c * LS << 9);
  f32x4 g[RW][RW];
#pragma unroll
  for (int ri = 0; ri < RW; ri++)
#pragma unroll
    for (int ci = 0; ci < RW; ci++) g[ri][ci] = {0.f, 0.f, 0.f, 0.f};

  for (int ch = 0; ch < 4; ch++) {
    __syncthreads();
    for (int idx = t; idx < LS * 16; idx += 256) {
      int row = idx >> 4, u = idx & 15;
      *(uint4*)(sm + row * 272 + u * 16) =
          ((const uint4*)(base + ((size_t)row << 9) + (ch << 7)))[u];
    }
    __syncthreads();
#pragma unroll
    for (int kk = 0; kk < 4; kk++) {
      short8 a[RW], b[RW];
#pragma unroll
      for (int ri = 0; ri < RW; ri++)
        a[ri] = *(const short8*)(sm + ((rT0 + ri) * 16 + m16) * 272 + kk * 64 + grp * 16);
#pragma unroll
      for (int ci = 0; ci < RW; ci++)
        b[ci] = *(const short8*)(sm + ((cT0 + ci) * 16 + m16) * 272 + kk * 64 + grp * 16);
#pragma unroll
      for (int ri = 0; ri < RW; ri++)
#pragma unroll
        for (int ci = 0; ci < RW; ci++)
          g[ri][ci] = __builtin_amdgcn_mfma_f32_16x16x32_bf16(a[ri], b[ci], g[ri][ci], 0, 0, 0);
    }
  }
#pragma unroll
  for (int ri = 0; ri < RW; ri++)
#pragma unroll
    for (int ci = 0; ci < RW; ci++)
#pragma unroll
      for (int r = 0; r < 4; r++) {
        int s = (rT0 + ri) * 16 + grp * 4 + r;
        int sp = (cT0 + ci) * 16 + m16;
        Gbf[(size_t)c * LS * LS + s * LS + sp] = f2bf(g[ri][ci][r]);
      }
}

__global__ __launch_bounds__(256, 2) void gram_all(
    const unsigned short* __restrict__ imn, const unsigned short* __restrict__ sn,
    unsigned short* __restrict__ Gim, unsigned short* __restrict__ Gs) {
  __shared__ __align__(16) char sm[64 * 272];
  if (blockIdx.x < 128) gram_body<64>(imn, Gim, blockIdx.x, sm);
  else gram_body<32>(sn, Gs, blockIdx.x - 128, sm);
}

// ---------------------------------------------------------------------------
// Kernel 3: macro-tiled fused attention — K6 body VERBATIM (best measured:
// 74 us/dispatch). G fragments in registers; one-pass softmax (analytic max);
// unnormalized e stored bf16; inv folded into epilogue.
// ---------------------------------------------------------------------------
template <int LS, int LQ, int GC, int GQ>
__global__ __launch_bounds__(256, 3) void attn_tile(
    const unsigned short* __restrict__ ctxn,  // (128,LS,512) bf16
    const unsigned short* __restrict__ qryn,  // (128,LQ,512) bf16
    const unsigned short* __restrict__ Gbf,   // (128,LS,LS) bf16
    const float* __restrict__ qnrm,           // 128*LQ raw query norms
    const float* __restrict__ cmask,          // (128,LS)
    float* __restrict__ sim) {
  static_assert(GC * LS == 128 && GQ * LQ == 128, "tile must be 128x128");
  constexpr int SROW = 144;                 // staging row stride (64 bf16 + pad)
  constexpr int S0P = 264;                  // S0/e row pitch (bytes)
  constexpr int FOFF = 256 * SROW;          // float scratch after staging
  constexpr int WPC = 4 / GC;               // waves per context in P3
  constexpr int KS3 = LS / 32;              // P3 k-steps: 2 (i2t) / 1 (t2i)
  static_assert(127 * S0P + 256 <= 256 * SROW, "S0 overflows staging alias");
  __shared__ __align__(16) char sm[FOFF + (GQ * 128 + 2 * GC * 128 + 512 + 256 + 8) * 4];
  float* rinvv = (float*)(sm + FOFF);       // [GQ][128]
  float* sumev = rinvv + GQ * 128;          // [GC][128]  sum e*v
  float* invv = sumev + GC * 128;           // [GC][128]  1/sum e
  float* psum = invv + GC * 128;            // [4][128] wn2 wave partials
  float* cmv = psum + 512;                  // [128]
  float* qnv = cmv + 128;                   // [128]
  float* cmmaxv = qnv + 128;                // [GC]

  const int bq = blockIdx.x, bc = blockIdx.y, t = threadIdx.x;
  const int w = t >> 6, lane = t & 63, m16 = lane & 15, grp = lane >> 4;

  auto soff = [](int n) { return n * S0P; };

  const unsigned short* aBase = ctxn + ((size_t)bc << 16);  // bc*128*512
  const unsigned short* bBase = qryn + ((size_t)bq << 16);

  // ---- preload cmask, qnorms; G fragments -> registers ----
  if (t < 128) cmv[t] = cmask[bc * 128 + t];
  else qnv[t - 128] = qnrm[bq * 128 + (t - 128)];
  const int c3 = w / WPC, hf = w % WPC;
  short8 g_a[2][KS3];
  {
    const unsigned short* gB = Gbf + (size_t)bc * GC * LS * LS + c3 * LS * LS;
#pragma unroll
    for (int mi = 0; mi < 2; mi++) {
      int sp = (hf * 2 + mi) * 16 + m16;
#pragma unroll
      for (int ks = 0; ks < KS3; ks++)
        g_a[mi][ks] = *(const short8*)(gB + sp * LS + ks * 32 + grp * 8);
    }
  }

  // shared accumulator file: P1 uses regs[si*4+ni], P3 uses regs[mi*8+nt]
  f32x4 regs[16];
#pragma unroll
  for (int i = 0; i < 16; i++) regs[i] = {0.f, 0.f, 0.f, 0.f};

  // ---- Phase 1: 128x128x512 score GEMM, 4x4 16-tiles per wave ----
  const int sT0 = (w & 1) * 4, nT0 = (w >> 1) * 4;
  for (int ch = 0; ch < 8; ch++) {
    __syncthreads();  // prior MFMA reads done
#pragma unroll
    for (int i = 0; i < 8; i++) {
      int idx = t + i * 256;
      int row = idx >> 3, u = idx & 7;
      const unsigned short* src =
          (row < 128) ? (aBase + ((size_t)row << 9)) : (bBase + ((size_t)(row - 128) << 9));
      *(uint4*)(sm + row * SROW + u * 16) = *(const uint4*)(src + ch * 64 + u * 8);
    }
    __syncthreads();  // staging ready
#pragma unroll
    for (int kk = 0; kk < 2; kk++) {
      short8 av[4], bv[4];
#pragma unroll
      for (int si = 0; si < 4; si++)
        av[si] = *(const short8*)(sm + ((sT0 + si) * 16 + m16) * SROW + kk * 64 + grp * 16);
#pragma unroll
      for (int ni = 0; ni < 4; ni++)
        bv[ni] = *(const short8*)(sm + (128 + (nT0 + ni) * 16 + m16) * SROW + kk * 64 + grp * 16);
#pragma unroll
      for (int si = 0; si < 4; si++)
#pragma unroll
        for (int ni = 0; ni < 4; ni++)
          regs[si * 4 + ni] = __builtin_amdgcn_mfma_f32_16x16x32_bf16(
              av[si], bv[ni], regs[si * 4 + ni], 0, 0, 0);
    }
  }
  __syncthreads();
  // write S0 bf16 [n][m]; C-layout rows (grp*4+r) are consecutive m -> 8B store
#pragma unroll
  for (int si = 0; si < 4; si++)
#pragma unroll
    for (int ni = 0; ni < 4; ni++) {
      int n = (nT0 + ni) * 16 + m16;
      int m0 = (sT0 + si) * 16 + grp * 4;
      f32x4 a = regs[si * 4 + ni];
      ushort4 p;
      p.x = f2bf(a[0]); p.y = f2bf(a[1]);
      p.z = f2bf(a[2]); p.w = f2bf(a[3]);
      *(ushort4*)(sm + soff(n) + m0 * 2) = p;
    }
  __syncthreads();

  // ---- Phase 2a: rinv (vectorized b64) + per-ci cmask max ----
  {
    if (t < GQ * 32) {
      int qi = t >> 5, mg = (t & 31) * 4;
      float s0 = 0.f, s1 = 0.f, s2 = 0.f, s3 = 0.f;
      for (int l = 0; l < LQ; l++) {
        uint2 pk = *(const uint2*)(sm + soff(qi * LQ + l) + mg * 2);
        float v0 = __uint_as_float(pk.x << 16);
        float v1 = __uint_as_float(pk.x & 0xffff0000u);
        float v2 = __uint_as_float(pk.y << 16);
        float v3 = __uint_as_float(pk.y & 0xffff0000u);
        v0 = v0 > 0.f ? v0 : 0.1f * v0;
        v1 = v1 > 0.f ? v1 : 0.1f * v1;
        v2 = v2 > 0.f ? v2 : 0.1f * v2;
        v3 = v3 > 0.f ? v3 : 0.1f * v3;
        s0 = fmaf(v0, v0, s0); s1 = fmaf(v1, v1, s1);
        s2 = fmaf(v2, v2, s2); s3 = fmaf(v3, v3, s3);
      }
      rinvv[qi * 128 + mg + 0] = 1.0f / (sqrtf(s0) + EPSF);
      rinvv[qi * 128 + mg + 1] = 1.0f / (sqrtf(s1) + EPSF);
      rinvv[qi * 128 + mg + 2] = 1.0f / (sqrtf(s2) + EPSF);
      rinvv[qi * 128 + mg + 3] = 1.0f / (sqrtf(s3) + EPSF);
    } else if (t < GQ * 32 + GC) {
      int ci = t - GQ * 32;
      float mx = cmv[ci * LS];
      for (int s = 1; s < LS; s++) mx = fmaxf(mx, cmv[ci * LS + s]);
      cmmaxv[ci] = mx;
    }
  }
  __syncthreads();

  // ---- Phase 2b: ONE-pass softmax (analytic max); store unnormalized e ----
  {
    const int n = t & 127;
    const int qi = n / LQ;
    for (int ci = t >> 7; ci < GC; ci += 2) {
      char* rowp = sm + soff(n) + ci * LS * 2;
      const float* rv = rinvv + qi * 128 + ci * LS;
      const float* cv = cmv + ci * LS;
      const float mxc = LAM * (1.0f + cmmaxv[ci]);
      float sum = 0.f, sev = 0.f;
#pragma unroll
      for (int u = 0; u < LS / 4; u++) {
        uint2 pk = *(const uint2*)(rowp + u * 8);
        float v0 = __uint_as_float(pk.x << 16);
        float v1 = __uint_as_float(pk.x & 0xffff0000u);
        float v2 = __uint_as_float(pk.y << 16);
        float v3 = __uint_as_float(pk.y & 0xffff0000u);
        int s = u * 4;
        float l0 = v0 > 0.f ? v0 : 0.1f * v0;
        float l1 = v1 > 0.f ? v1 : 0.1f * v1;
        float l2 = v2 > 0.f ? v2 : 0.1f * v2;
        float l3 = v3 > 0.f ? v3 : 0.1f * v3;
        float e0 = __expf(LAM * fmaf(l0, rv[s + 0], cv[s + 0]) - mxc);
        float e1 = __expf(LAM * fmaf(l1, rv[s + 1], cv[s + 1]) - mxc);
        float e2 = __expf(LAM * fmaf(l2, rv[s + 2], cv[s + 2]) - mxc);
        float e3 = __expf(LAM * fmaf(l3, rv[s + 3], cv[s + 3]) - mxc);
        sum += (e0 + e1) + (e2 + e3);
        sev = fmaf(e0, v0, sev); sev = fmaf(e1, v1, sev);
        sev = fmaf(e2, v2, sev); sev = fmaf(e3, v3, sev);
        uint2 o;
        o.x = (unsigned)f2bf(e0) | ((unsigned)f2bf(e1) << 16);
        o.y = (unsigned)f2bf(e2) | ((unsigned)f2bf(e3) << 16);
        *(uint2*)(rowp + u * 8) = o;
      }
      sumev[ci * 128 + n] = sev;
      invv[ci * 128 + n] = 1.0f / sum;
    }
  }
  __syncthreads();

  // ---- Phase 3: per-c U = G_c @ e_c (MFMA, A from regs); wn2 from C-regs ----
  {
#pragma unroll
    for (int i = 0; i < 16; i++) regs[i] = {0.f, 0.f, 0.f, 0.f};
#pragma unroll
    for (int ks = 0; ks < KS3; ks++) {
      short8 b2[8];
#pragma unroll
      for (int nt = 0; nt < 8; nt++) {
        const char* p = sm + soff(nt * 16 + m16) + c3 * LS * 2 + ks * 64 + grp * 16;
        union { uint2 h[2]; short8 v; } bb;
        bb.h[0] = *(const uint2*)(p);
        bb.h[1] = *(const uint2*)(p + 8);
        b2[nt] = bb.v;
      }
#pragma unroll
      for (int mi = 0; mi < 2; mi++)
#pragma unroll
        for (int nt = 0; nt < 8; nt++)
          regs[mi * 8 + nt] = __builtin_amdgcn_mfma_f32_16x16x32_bf16(
              g_a[mi][ks], b2[nt], regs[mi * 8 + nt], 0, 0, 0);
    }
    float wp[8];
#pragma unroll
    for (int nt = 0; nt < 8; nt++) wp[nt] = 0.f;
#pragma unroll
    for (int nt = 0; nt < 8; nt++) {
#pragma unroll
      for (int mi = 0; mi < 2; mi++) {
        int sp = (hf * 2 + mi) * 16 + grp * 4;
        uint2 ee = *(const uint2*)(sm + soff(nt * 16 + m16) + (c3 * LS + sp) * 2);
        f32x4 uu = regs[mi * 8 + nt];
        wp[nt] += __uint_as_float(ee.x << 16) * uu[0] +
                  __uint_as_float(ee.x & 0xffff0000u) * uu[1] +
                  __uint_as_float(ee.y << 16) * uu[2] +
                  __uint_as_float(ee.y & 0xffff0000u) * uu[3];
      }
    }
#pragma unroll
    for (int o = 16; o < 64; o <<= 1)
#pragma unroll
      for (int nt = 0; nt < 8; nt++) wp[nt] += __shfl_xor(wp[nt], o);
    if (lane < 16) {
#pragma unroll
      for (int nt = 0; nt < 8; nt++) psum[w * 128 + nt * 16 + lane] = wp[nt];
    }
  }
  __syncthreads();

  // ---- Final: cos + mean over l -> sim ----
  {
    const int p = t >> 5, l0 = t & 31;
    const int cc = p / GQ, qi = p % GQ;
    float sum = 0.f;
#pragma unroll
    for (int li = 0; li < LQ / 32; li++) {
      int n = qi * LQ + l0 + li * 32;
      float nq = qnv[n];
      float inv = invv[cc * 128 + n];
      float w12 = sumev[cc * 128 + n] * inv;
      float wn2u = 0.f;
#pragma unroll
      for (int h = 0; h < WPC; h++) wn2u += psum[(cc * WPC + h) * 128 + n];
      float wn2 = wn2u * inv * inv;
      float denom = fmaxf(nq * sqrtf(fmaxf(wn2, 0.f)), 1e-8f);
      sum += (nq + EPSF) * w12 / denom;
    }
#pragma unroll
    for (int o = 1; o < 32; o <<= 1) sum += __shfl_xor(sum, o);
    if (l0 == 0) sim[(bc * GC + cc) * 128 + bq * GQ + qi] = sum * (1.0f / (float)LQ);
  }
}

// ---------------------------------------------------------------------------
// Kernel 4: fused loss — per-row terms + device-scope atomic accumulation;
// last-arriving block finalizes out[0..2]. acc[0..2]=sums, acc[3]=counter
// (zeroed via hipMemsetAsync before launch).
// ---------------------------------------------------------------------------
__global__ __launch_bounds__(128) void loss_fused(
    const float* __restrict__ gsim, const float* __restrict__ i2t,
    const float* __restrict__ t2i, float* __restrict__ acc,
    float* __restrict__ out) {
  const int i = blockIdx.x, j = threadIdx.x;
  const int B = 128;
  __shared__ float sh[2];
  auto bmax = [&](float v) -> float {
#pragma unroll
    for (int o = 32; o; o >>= 1) v = fmaxf(v, __shfl_down(v, o));
    if ((j & 63) == 0) sh[j >> 6] = v;
    __syncthreads();
    float r = fmaxf(sh[0], sh[1]);
    __syncthreads();
    return r;
  };
  auto bsum = [&](float v) -> float {
#pragma unroll
    for (int o = 32; o; o >>= 1) v += __shfl_down(v, o);
    if ((j & 63) == 0) sh[j >> 6] = v;
    __syncthreads();
    float r = sh[0] + sh[1];
    __syncthreads();
    return r;
  };
  float xr = gsim[i * B + j] * 20.f;
  float xc = gsim[j * B + i] * 20.f;
  float sc = (i2t[i * B + j] + t2i[j * B + i]) * LAM;
  float mr = bmax(xr);
  float lser = mr + logf(bsum(__expf(xr - mr)));
  float mc = bmax(xc);
  float lsec = mc + logf(bsum(__expf(xc - mc)));
  float ml = bmax(sc);
  float lsel = ml + logf(bsum(__expf(sc - ml)));
  float pred = __expf(sc - lsel);
  float logLab = (i == j) ? logf(1.0f + 1e-6f) : logf(1e-6f);
  float tsum = bsum(pred * (sc - lsel - logLab));
  if (j == 0) {
    float d = gsim[i * B + i] * 20.f;
    atomicAdd(&acc[0], d - lser);
    atomicAdd(&acc[1], d - lsec);
    atomicAdd(&acc[2], tsum);
    __threadfence();
    unsigned old = atomicAdd((unsigned*)&acc[3], 1u);
    if (old == 127u) {
      __threadfence();
      float a = acc[0], b = acc[1], c = acc[2];
      float gl = -(a / 128.f) - (b / 128.f);
      float ll = c / 128.f;
      out[0] = gl + ll;
      out[1] = gl;
      out[2] = ll;
    }
  }
}

extern "C" void kernel_launch(void* const* d_in, const int* in_sizes, int n_in,
                              void* d_out, int out_size, void* d_ws,
                              size_t ws_size, hipStream_t stream) {
  const float* gsim = (const float*)d_in[0];  // (128,128)
  const float* im = (const float*)d_in[1];    // (128,64,512)
  const float* s = (const float*)d_in[2];     // (128,32,512)
  const float* im_m = (const float*)d_in[3];  // (128,64)
  const float* s_m = (const float*)d_in[5];   // (128,32)
  float* out = (float*)d_out;

  float* ws = (float*)d_ws;
  float* nim = ws;                                         // 8192
  float* ns = ws + 8192;                                   // 4096
  float* i2t = ws + 12288;                                 // 16384
  float* t2i = ws + 28672;                                 // 16384
  float* acc = ws + 45056;                                 // 4 (sums + counter)
  unsigned short* Gim = (unsigned short*)(ws + 45440);     // 128*64*64 bf16
  unsigned short* Gs = (unsigned short*)(ws + 307584);     // 128*32*32 bf16
  unsigned short* imn = (unsigned short*)(ws + 373120);    // 128*64*512 bf16
  unsigned short* sn = (unsigned short*)(ws + 2470272);    // 128*32*512 bf16

  hipMemsetAsync(acc, 0, 16, stream);  // zero atomic accumulators (graph-safe)
  norm_convert<<<dim3(3072), dim3(256), 0, stream>>>(im, s, nim, ns, imn, sn);
  gram_all<<<dim3(256), dim3(256), 0, stream>>>(imn, sn, Gim, Gs);
  // i2t: ctx=images(LS=64,GC=2), qry=captions(LQ=32,GQ=4)
  attn_tile<64, 32, 2, 4><<<dim3(32, 64), dim3(256), 0, stream>>>(
      imn, sn, Gim, ns, im_m, i2t);
  // t2i: ctx=captions(LS=32,GC=4), qry=images(LQ=64,GQ=2)
  attn_tile<32, 64, 4, 2><<<dim3(64, 32), dim3(256), 0, stream>>>(
      sn, imn, Gs, nim, s_m, t2i);
  loss_fused<<<dim3(128), dim3(128), 0, stream>>>(gsim, i2t, t2i, acc, out);
}

// Round 12
// 215.458 us; speedup vs baseline: 1.6608x; 1.0564x over previous
//
#include <hip/hip_runtime.h>
#include <math.h>

#define EPSF 1e-8f
#define LAM 20.0f

typedef short short8 __attribute__((ext_vector_type(8)));
typedef float f32x4 __attribute__((ext_vector_type(4)));

__device__ __forceinline__ unsigned short f2bf(float x) {
  unsigned u = __float_as_uint(x);
  u += 0x7fffu + ((u >> 16) & 1u);
  return (unsigned short)(u >> 16);
}
__device__ __forceinline__ float bf2f(unsigned short h) {
  return __uint_as_float(((unsigned)h) << 16);
}

// ---------------------------------------------------------------------------
// Kernel 1: row norms + bf16 normalized copies (+ zero the loss accumulators).
// ---------------------------------------------------------------------------
__global__ __launch_bounds__(256) void norm_convert(
    const float* __restrict__ im, const float* __restrict__ s,
    float* __restrict__ nim, float* __restrict__ ns,
    unsigned short* __restrict__ imn, unsigned short* __restrict__ sn,
    float* __restrict__ acc) {
  if (blockIdx.x == 0 && threadIdx.x < 4) acc[threadIdx.x] = 0.f;
  int row = blockIdx.x * 4 + (threadIdx.x >> 6);
  int lane = threadIdx.x & 63;
  const float* src;
  unsigned short* dst;
  float* ndst;
  if (row < 8192) {
    src = im + ((size_t)row << 9);
    dst = imn + ((size_t)row << 9);
    ndst = nim + row;
  } else {
    int r = row - 8192;
    src = s + ((size_t)r << 9);
    dst = sn + ((size_t)r << 9);
    ndst = ns + r;
  }
  float4 v0 = ((const float4*)src)[lane * 2];
  float4 v1 = ((const float4*)src)[lane * 2 + 1];
  float ss = 0.f;
  ss = fmaf(v0.x, v0.x, ss); ss = fmaf(v0.y, v0.y, ss);
  ss = fmaf(v0.z, v0.z, ss); ss = fmaf(v0.w, v0.w, ss);
  ss = fmaf(v1.x, v1.x, ss); ss = fmaf(v1.y, v1.y, ss);
  ss = fmaf(v1.z, v1.z, ss); ss = fmaf(v1.w, v1.w, ss);
#pragma unroll
  for (int o = 32; o; o >>= 1) ss += __shfl_xor(ss, o);
  float n = sqrtf(ss);
  if (lane == 0) *ndst = n;
  float ci = 1.0f / (n + EPSF);
  union { unsigned short us[8]; uint4 v; } p;
  p.us[0] = f2bf(v0.x * ci); p.us[1] = f2bf(v0.y * ci);
  p.us[2] = f2bf(v0.z * ci); p.us[3] = f2bf(v0.w * ci);
  p.us[4] = f2bf(v1.x * ci); p.us[5] = f2bf(v1.y * ci);
  p.us[6] = f2bf(v1.z * ci); p.us[7] = f2bf(v1.w * ci);
  ((uint4*)dst)[lane] = p.v;
}

// ---------------------------------------------------------------------------
// Kernel 2: bf16 Gram matrices via MFMA (LDS-staged bodies), one launch.
// ---------------------------------------------------------------------------
template <int LS>
__device__ __forceinline__ void gram_body(const unsigned short* __restrict__ ctxn,
                                          unsigned short* __restrict__ Gbf,
                                          int c, char* sm) {
  constexpr int RW = (LS / 16) / 2;
  const int t = threadIdx.x;
  const int w = t >> 6, lane = t & 63, m16 = lane & 15, grp = lane >> 4;
  const int rT0 = (w & 1) * RW, cT0 = (w >> 1) * RW;
  const unsigned short* base = ctxn + ((size_t)c * LS << 9);
  f32x4 g[RW][RW];
#pragma unroll
  for (int ri = 0; ri < RW; ri++)
#pragma unroll
    for (int ci = 0; ci < RW; ci++) g[ri][ci] = {0.f, 0.f, 0.f, 0.f};

  for (int ch = 0; ch < 4; ch++) {
    __syncthreads();
    for (int idx = t; idx < LS * 16; idx += 256) {
      int row = idx >> 4, u = idx & 15;
      *(uint4*)(sm + row * 272 + u * 16) =
          ((const uint4*)(base + ((size_t)row << 9) + (ch << 7)))[u];
    }
    __syncthreads();
#pragma unroll
    for (int kk = 0; kk < 4; kk++) {
      short8 a[RW], b[RW];
#pragma unroll
      for (int ri = 0; ri < RW; ri++)
        a[ri] = *(const short8*)(sm + ((rT0 + ri) * 16 + m16) * 272 + kk * 64 + grp * 16);
#pragma unroll
      for (int ci = 0; ci < RW; ci++)
        b[ci] = *(const short8*)(sm + ((cT0 + ci) * 16 + m16) * 272 + kk * 64 + grp * 16);
#pragma unroll
      for (int ri = 0; ri < RW; ri++)
#pragma unroll
        for (int ci = 0; ci < RW; ci++)
          g[ri][ci] = __builtin_amdgcn_mfma_f32_16x16x32_bf16(a[ri], b[ci], g[ri][ci], 0, 0, 0);
    }
  }
#pragma unroll
  for (int ri = 0; ri < RW; ri++)
#pragma unroll
    for (int ci = 0; ci < RW; ci++)
#pragma unroll
      for (int r = 0; r < 4; r++) {
        int s = (rT0 + ri) * 16 + grp * 4 + r;
        int sp = (cT0 + ci) * 16 + m16;
        Gbf[(size_t)c * LS * LS + s * LS + sp] = f2bf(g[ri][ci][r]);
      }
}

__global__ __launch_bounds__(256, 2) void gram_all(
    const unsigned short* __restrict__ imn, const unsigned short* __restrict__ sn,
    unsigned short* __restrict__ Gim, unsigned short* __restrict__ Gs) {
  __shared__ __align__(16) char sm[64 * 272];
  if (blockIdx.x < 128) gram_body<64>(imn, Gim, blockIdx.x, sm);
  else gram_body<32>(sn, Gs, blockIdx.x - 128, sm);
}

// ---------------------------------------------------------------------------
// Kernel 3: PAIRED attention. One block computes the 128x128 raw score tile
// S0[cap n][img m] ONCE (transpose symmetry: i2t tile == t2i tile^T,
// bit-identical MFMA results), then runs BOTH directions' post-processing.
//   i2t (ctx=img GC=2, qry=cap GQ=4): K6 phases verbatim (in-place e, MFMA P3).
//   t2i (ctx=cap 4x32, qry=img 2x64): store-free fused pass — per (img col,
//   cap ctx) task: e[32] in registers, wn2 = e^T G_s e scalar (G_s bf16 LDS,
//   lane-broadcast rows), w12/wn2 -> scratch; then final.
// LDS: staging 36864 (S0 aliases) + G_s 8192 (psum aliases) + scratch 8224
//    = 53280 B -> 3 blocks/CU.
// ---------------------------------------------------------------------------
__global__ __launch_bounds__(256, 3) void attn_pair(
    const unsigned short* __restrict__ imn, const unsigned short* __restrict__ sn,
    const unsigned short* __restrict__ Gim, const unsigned short* __restrict__ Gs,
    const float* __restrict__ nim, const float* __restrict__ ns,
    const float* __restrict__ im_m, const float* __restrict__ s_m,
    float* __restrict__ i2t, float* __restrict__ t2i) {
  constexpr int SROW = 144;
  constexpr int S0P = 264;
  constexpr int GOFF = 256 * SROW;   // 36864: G_s bf16 (8 KB); psum aliases later
  constexpr int FOFF = GOFF + 8192;  // 45056: float scratch
  __shared__ __align__(16) char sm[FOFF + 2056 * 4];
  float* F = (float*)(sm + FOFF);
  float* rinv_i = F;          // [4][128] (persistent)
  float* cmv_i = F + 512;     // [128]    (persistent)
  float* cmmax_i = F + 640;   // [2]+pad
  float* rinv_t = F + 644;    // [2][128] (t2i) | alias: sumev_i [2][128]
  float* w12t = F + 900;      // [4][128] (t2i) | alias: invv_i  [2][128]
  float* wn2t = F + 1412;     // [4][128]
  float* cmv_t = F + 1924;    // [128]
  float* cmmax_t = F + 2052;  // [4]
  float* sumev_i = F + 644;
  float* invv_i = F + 900;
  float* psum = (float*)(sm + GOFF);  // [4][128] (i2t P3; G_s dead by then)

  const int bq = blockIdx.x;  // caption block: 4 cap ctxs = 128 cap rows
  const int bc = blockIdx.y;  // image block:   2 img ctxs = 128 img rows
  const int t = threadIdx.x;
  const int w = t >> 6, lane = t & 63, m16 = lane & 15, grp = lane >> 4;
  auto soff = [](int n) { return n * S0P; };

  const unsigned short* aBase = imn + ((size_t)bc << 16);  // img rows (ctx for i2t)
  const unsigned short* bBase = sn + ((size_t)bq << 16);   // cap rows (qry for i2t)

  // ---- preload masks, G_s -> LDS, G_im fragments -> registers ----
  if (t < 128) cmv_i[t] = im_m[bc * 128 + t];
  else cmv_t[t - 128] = s_m[bq * 128 + (t - 128)];
  {
    const uint4* gs = (const uint4*)(Gs + ((size_t)bq << 12));  // 4 ctx x 1024
    ((uint4*)(sm + GOFF))[t] = gs[t];
    ((uint4*)(sm + GOFF))[t + 256] = gs[t + 256];
  }
  const int c3 = w >> 1, hf = w & 1;  // i2t P3: WPC=2
  short8 g_a[2][2];
  {
    const unsigned short* gB = Gim + ((size_t)bc * 2 + c3) * 4096;
#pragma unroll
    for (int mi = 0; mi < 2; mi++) {
      int sp = (hf * 2 + mi) * 16 + m16;
#pragma unroll
      for (int ks = 0; ks < 2; ks++)
        g_a[mi][ks] = *(const short8*)(gB + sp * 64 + ks * 32 + grp * 8);
    }
  }

  f32x4 regs[16];
#pragma unroll
  for (int i = 0; i < 16; i++) regs[i] = {0.f, 0.f, 0.f, 0.f};

  // ---- Phase 1: 128x128x512 score GEMM (K6 verbatim) ----
  const int sT0 = (w & 1) * 4, nT0 = (w >> 1) * 4;
  for (int ch = 0; ch < 8; ch++) {
    __syncthreads();
#pragma unroll
    for (int i = 0; i < 8; i++) {
      int idx = t + i * 256;
      int row = idx >> 3, u = idx & 7;
      const unsigned short* src =
          (row < 128) ? (aBase + ((size_t)row << 9)) : (bBase + ((size_t)(row - 128) << 9));
      *(uint4*)(sm + row * SROW + u * 16) = *(const uint4*)(src + ch * 64 + u * 8);
    }
    __syncthreads();
#pragma unroll
    for (int kk = 0; kk < 2; kk++) {
      short8 av[4], bv[4];
#pragma unroll
      for (int si = 0; si < 4; si++)
        av[si] = *(const short8*)(sm + ((sT0 + si) * 16 + m16) * SROW + kk * 64 + grp * 16);
#pragma unroll
      for (int ni = 0; ni < 4; ni++)
        bv[ni] = *(const short8*)(sm + (128 + (nT0 + ni) * 16 + m16) * SROW + kk * 64 + grp * 16);
#pragma unroll
      for (int si = 0; si < 4; si++)
#pragma unroll
        for (int ni = 0; ni < 4; ni++)
          regs[si * 4 + ni] = __builtin_amdgcn_mfma_f32_16x16x32_bf16(
              av[si], bv[ni], regs[si * 4 + ni], 0, 0, 0);
    }
  }
  __syncthreads();
  // S0 bf16 [n=cap][m=img]
#pragma unroll
  for (int si = 0; si < 4; si++)
#pragma unroll
    for (int ni = 0; ni < 4; ni++) {
      int n = (nT0 + ni) * 16 + m16;
      int m0 = (sT0 + si) * 16 + grp * 4;
      f32x4 a = regs[si * 4 + ni];
      ushort4 p;
      p.x = f2bf(a[0]); p.y = f2bf(a[1]);
      p.z = f2bf(a[2]); p.w = f2bf(a[3]);
      *(ushort4*)(sm + soff(n) + m0 * 2) = p;
    }
  __syncthreads();

  // ---- rinv stage: i2t rinv (threads 0..127), t2i rinv (threads 128..255),
  //      cmmax by threads 0..5 ----
  if (t < 128) {
    if (t < 2) {
      float mx = cmv_i[t * 64];
      for (int s = 1; s < 64; s++) mx = fmaxf(mx, cmv_i[t * 64 + s]);
      cmmax_i[t] = mx;
    } else if (t < 6) {
      int ci = t - 2;
      float mx = cmv_t[ci * 32];
      for (int s = 1; s < 32; s++) mx = fmaxf(mx, cmv_t[ci * 32 + s]);
      cmmax_t[ci] = mx;
    }
    int qi = t >> 5, mg = (t & 31) * 4;
    float s0 = 0.f, s1 = 0.f, s2 = 0.f, s3 = 0.f;
    for (int l = 0; l < 32; l++) {
      uint2 pk = *(const uint2*)(sm + soff(qi * 32 + l) + mg * 2);
      float v0 = __uint_as_float(pk.x << 16);
      float v1 = __uint_as_float(pk.x & 0xffff0000u);
      float v2 = __uint_as_float(pk.y << 16);
      float v3 = __uint_as_float(pk.y & 0xffff0000u);
      v0 = v0 > 0.f ? v0 : 0.1f * v0;
      v1 = v1 > 0.f ? v1 : 0.1f * v1;
      v2 = v2 > 0.f ? v2 : 0.1f * v2;
      v3 = v3 > 0.f ? v3 : 0.1f * v3;
      s0 = fmaf(v0, v0, s0); s1 = fmaf(v1, v1, s1);
      s2 = fmaf(v2, v2, s2); s3 = fmaf(v3, v3, s3);
    }
    rinv_i[qi * 128 + mg + 0] = 1.0f / (sqrtf(s0) + EPSF);
    rinv_i[qi * 128 + mg + 1] = 1.0f / (sqrtf(s1) + EPSF);
    rinv_i[qi * 128 + mg + 2] = 1.0f / (sqrtf(s2) + EPSF);
    rinv_i[qi * 128 + mg + 3] = 1.0f / (sqrtf(s3) + EPSF);
  } else {
    int n = t - 128;  // cap row
#pragma unroll
    for (int qi = 0; qi < 2; qi++) {
      float ss = 0.f;
#pragma unroll 4
      for (int j = 0; j < 16; j++) {
        uint2 pk = *(const uint2*)(sm + soff(n) + qi * 128 + j * 8);
        float v0 = __uint_as_float(pk.x << 16);
        float v1 = __uint_as_float(pk.x & 0xffff0000u);
        float v2 = __uint_as_float(pk.y << 16);
        float v3 = __uint_as_float(pk.y & 0xffff0000u);
        v0 = v0 > 0.f ? v0 : 0.1f * v0;
        v1 = v1 > 0.f ? v1 : 0.1f * v1;
        v2 = v2 > 0.f ? v2 : 0.1f * v2;
        v3 = v3 > 0.f ? v3 : 0.1f * v3;
        ss = fmaf(v0, v0, ss); ss = fmaf(v1, v1, ss);
        ss = fmaf(v2, v2, ss); ss = fmaf(v3, v3, ss);
      }
      rinv_t[qi * 128 + n] = 1.0f / (sqrtf(ss) + EPSF);
    }
  }
  __syncthreads();

  // ---- t2i fused pass: per (cap ctx ci, img col mp): e in regs,
  //      wn2 = e^T G_s e, w12 — no e store (raw S0 preserved) ----
#pragma unroll
  for (int rep = 0; rep < 2; rep++) {
    int task = t + rep * 256;
    int ci = task >> 7, mp = task & 127;
    int qi = mp >> 6;
    const float mxc = LAM * (1.0f + cmmax_t[ci]);
    const float* rv = rinv_t + qi * 128 + ci * 32;
    const float* cv = cmv_t + ci * 32;
    float e[32];
    float sum = 0.f, sev = 0.f;
#pragma unroll
    for (int s = 0; s < 32; s++) {
      float v = bf2f(*(const unsigned short*)(sm + soff(ci * 32 + s) + mp * 2));
      float lv = v > 0.f ? v : 0.1f * v;
      float ee = __expf(LAM * fmaf(lv, rv[s], cv[s]) - mxc);
      e[s] = ee;
      sum += ee;
      sev = fmaf(ee, v, sev);
    }
    float wn2 = 0.f;
    const char* gRow = sm + GOFF + ci * 2048;
#pragma unroll 4
    for (int s1 = 0; s1 < 32; s1++) {
      const uint2* gp = (const uint2*)(gRow + s1 * 64);
      float u = 0.f;
#pragma unroll
      for (int k = 0; k < 8; k++) {
        uint2 gg = gp[k];
        u = fmaf(__uint_as_float(gg.x << 16), e[4 * k + 0], u);
        u = fmaf(__uint_as_float(gg.x & 0xffff0000u), e[4 * k + 1], u);
        u = fmaf(__uint_as_float(gg.y << 16), e[4 * k + 2], u);
        u = fmaf(__uint_as_float(gg.y & 0xffff0000u), e[4 * k + 3], u);
      }
      wn2 = fmaf(e[s1], u, wn2);
    }
    float inv = 1.0f / sum;
    w12t[ci * 128 + mp] = sev * inv;
    wn2t[ci * 128 + mp] = wn2 * inv * inv;
  }
  __syncthreads();

  // ---- t2i final: cos + mean over 64 img words -> t2i sim ----
  {
    const int p = t >> 5, l0 = t & 31;
    const int cc = p >> 1, qi = p & 1;
    float sum = 0.f;
#pragma unroll
    for (int li = 0; li < 2; li++) {
      int n = qi * 64 + l0 + li * 32;
      float nq = nim[bc * 128 + n];
      float w12 = w12t[cc * 128 + n];
      float wn2 = wn2t[cc * 128 + n];
      float denom = fmaxf(nq * sqrtf(fmaxf(wn2, 0.f)), 1e-8f);
      sum += (nq + EPSF) * w12 / denom;
    }
#pragma unroll
    for (int o = 1; o < 32; o <<= 1) sum += __shfl_xor(sum, o);
    if (l0 == 0) t2i[(bq * 4 + cc) * 128 + bc * 2 + qi] = sum * (1.0f / 64.f);
  }
  __syncthreads();  // w12t/rinv_t regions die; sumev_i/invv_i alias them

  // ---- i2t 2b: one-pass softmax in place (K6 verbatim) ----
  {
    const int n = t & 127;
    const int qi = n >> 5;
    const int ci = t >> 7;  // GC=2, one ci per thread
    char* rowp = sm + soff(n) + ci * 128;
    const float* rv = rinv_i + qi * 128 + ci * 64;
    const float* cv = cmv_i + ci * 64;
    const float mxc = LAM * (1.0f + cmmax_i[ci]);
    float sum = 0.f, sev = 0.f;
#pragma unroll
    for (int u = 0; u < 16; u++) {
      uint2 pk = *(const uint2*)(rowp + u * 8);
      float v0 = __uint_as_float(pk.x << 16);
      float v1 = __uint_as_float(pk.x & 0xffff0000u);
      float v2 = __uint_as_float(pk.y << 16);
      float v3 = __uint_as_float(pk.y & 0xffff0000u);
      int s = u * 4;
      float l0 = v0 > 0.f ? v0 : 0.1f * v0;
      float l1 = v1 > 0.f ? v1 : 0.1f * v1;
      float l2 = v2 > 0.f ? v2 : 0.1f * v2;
      float l3 = v3 > 0.f ? v3 : 0.1f * v3;
      float e0 = __expf(LAM * fmaf(l0, rv[s + 0], cv[s + 0]) - mxc);
      float e1 = __expf(LAM * fmaf(l1, rv[s + 1], cv[s + 1]) - mxc);
      float e2 = __expf(LAM * fmaf(l2, rv[s + 2], cv[s + 2]) - mxc);
      float e3 = __expf(LAM * fmaf(l3, rv[s + 3], cv[s + 3]) - mxc);
      sum += (e0 + e1) + (e2 + e3);
      sev = fmaf(e0, v0, sev); sev = fmaf(e1, v1, sev);
      sev = fmaf(e2, v2, sev); sev = fmaf(e3, v3, sev);
      uint2 o;
      o.x = (unsigned)f2bf(e0) | ((unsigned)f2bf(e1) << 16);
      o.y = (unsigned)f2bf(e2) | ((unsigned)f2bf(e3) << 16);
      *(uint2*)(rowp + u * 8) = o;
    }
    sumev_i[ci * 128 + n] = sev;
    invv_i[ci * 128 + n] = 1.0f / sum;
  }
  __syncthreads();

  // ---- i2t P3: U = G_im @ e (MFMA, A from regs); wn2 from C-regs ----
  {
#pragma unroll
    for (int i = 0; i < 16; i++) regs[i] = {0.f, 0.f, 0.f, 0.f};
#pragma unroll
    for (int ks = 0; ks < 2; ks++) {
      short8 b2[8];
#pragma unroll
      for (int nt = 0; nt < 8; nt++) {
        const char* p = sm + soff(nt * 16 + m16) + c3 * 128 + ks * 64 + grp * 16;
        union { uint2 h[2]; short8 v; } bb;
        bb.h[0] = *(const uint2*)(p);
        bb.h[1] = *(const uint2*)(p + 8);
        b2[nt] = bb.v;
      }
#pragma unroll
      for (int mi = 0; mi < 2; mi++)
#pragma unroll
        for (int nt = 0; nt < 8; nt++)
          regs[mi * 8 + nt] = __builtin_amdgcn_mfma_f32_16x16x32_bf16(
              g_a[mi][ks], b2[nt], regs[mi * 8 + nt], 0, 0, 0);
    }
    float wp[8];
#pragma unroll
    for (int nt = 0; nt < 8; nt++) wp[nt] = 0.f;
#pragma unroll
    for (int nt = 0; nt < 8; nt++) {
#pragma unroll
      for (int mi = 0; mi < 2; mi++) {
        int sp = (hf * 2 + mi) * 16 + grp * 4;
        uint2 ee = *(const uint2*)(sm + soff(nt * 16 + m16) + (c3 * 64 + sp) * 2);
        f32x4 uu = regs[mi * 8 + nt];
        wp[nt] += __uint_as_float(ee.x << 16) * uu[0] +
                  __uint_as_float(ee.x & 0xffff0000u) * uu[1] +
                  __uint_as_float(ee.y << 16) * uu[2] +
                  __uint_as_float(ee.y & 0xffff0000u) * uu[3];
      }
    }
#pragma unroll
    for (int o = 16; o < 64; o <<= 1)
#pragma unroll
      for (int nt = 0; nt < 8; nt++) wp[nt] += __shfl_xor(wp[nt], o);
    if (lane < 16) {
#pragma unroll
      for (int nt = 0; nt < 8; nt++) psum[w * 128 + nt * 16 + lane] = wp[nt];
    }
  }
  __syncthreads();

  // ---- i2t final: cos + mean over 32 cap words -> i2t sim ----
  {
    const int p = t >> 5, l0 = t & 31;
    const int cc = p >> 2, qi = p & 3;
    int n = qi * 32 + l0;
    float nq = ns[bq * 128 + n];
    float inv = invv_i[cc * 128 + n];
    float w12 = sumev_i[cc * 128 + n] * inv;
    float wn2u = psum[(cc * 2 + 0) * 128 + n] + psum[(cc * 2 + 1) * 128 + n];
    float wn2 = wn2u * inv * inv;
    float denom = fmaxf(nq * sqrtf(fmaxf(wn2, 0.f)), 1e-8f);
    float sum = (nq + EPSF) * w12 / denom;
#pragma unroll
    for (int o = 1; o < 32; o <<= 1) sum += __shfl_xor(sum, o);
    if (l0 == 0) i2t[(bc * 2 + cc) * 128 + bq * 4 + qi] = sum * (1.0f / 32.f);
  }
}

// ---------------------------------------------------------------------------
// Kernel 4: fused loss (R11-proven).
// ---------------------------------------------------------------------------
__global__ __launch_bounds__(128) void loss_fused(
    const float* __restrict__ gsim, const float* __restrict__ i2t,
    const float* __restrict__ t2i, float* __restrict__ acc,
    float* __restrict__ out) {
  const int i = blockIdx.x, j = threadIdx.x;
  const int B = 128;
  __shared__ float sh[2];
  auto bmax = [&](float v) -> float {
#pragma unroll
    for (int o = 32; o; o >>= 1) v = fmaxf(v, __shfl_down(v, o));
    if ((j & 63) == 0) sh[j >> 6] = v;
    __syncthreads();
    float r = fmaxf(sh[0], sh[1]);
    __syncthreads();
    return r;
  };
  auto bsum = [&](float v) -> float {
#pragma unroll
    for (int o = 32; o; o >>= 1) v += __shfl_down(v, o);
    if ((j & 63) == 0) sh[j >> 6] = v;
    __syncthreads();
    float r = sh[0] + sh[1];
    __syncthreads();
    return r;
  };
  float xr = gsim[i * B + j] * 20.f;
  float xc = gsim[j * B + i] * 20.f;
  float sc = (i2t[i * B + j] + t2i[j * B + i]) * LAM;
  float mr = bmax(xr);
  float lser = mr + logf(bsum(__expf(xr - mr)));
  float mc = bmax(xc);
  float lsec = mc + logf(bsum(__expf(xc - mc)));
  float ml = bmax(sc);
  float lsel = ml + logf(bsum(__expf(sc - ml)));
  float pred = __expf(sc - lsel);
  float logLab = (i == j) ? logf(1.0f + 1e-6f) : logf(1e-6f);
  float tsum = bsum(pred * (sc - lsel - logLab));
  if (j == 0) {
    float d = gsim[i * B + i] * 20.f;
    atomicAdd(&acc[0], d - lser);
    atomicAdd(&acc[1], d - lsec);
    atomicAdd(&acc[2], tsum);
    __threadfence();
    unsigned old = atomicAdd((unsigned*)&acc[3], 1u);
    if (old == 127u) {
      __threadfence();
      float a = acc[0], b = acc[1], c = acc[2];
      float gl = -(a / 128.f) - (b / 128.f);
      float ll = c / 128.f;
      out[0] = gl + ll;
      out[1] = gl;
      out[2] = ll;
    }
  }
}

extern "C" void kernel_launch(void* const* d_in, const int* in_sizes, int n_in,
                              void* d_out, int out_size, void* d_ws,
                              size_t ws_size, hipStream_t stream) {
  const float* gsim = (const float*)d_in[0];  // (128,128)
  const float* im = (const float*)d_in[1];    // (128,64,512)
  const float* s = (const float*)d_in[2];     // (128,32,512)
  const float* im_m = (const float*)d_in[3];  // (128,64)
  const float* s_m = (const float*)d_in[5];   // (128,32)
  float* out = (float*)d_out;

  float* ws = (float*)d_ws;
  float* nim = ws;                                         // 8192
  float* ns = ws + 8192;                                   // 4096
  float* i2t = ws + 12288;                                 // 16384
  float* t2i = ws + 28672;                                 // 16384
  float* acc = ws + 45056;                                 // 4
  unsigned short* Gim = (unsigned short*)(ws + 45440);     // 128*64*64 bf16
  unsigned short* Gs = (unsigned short*)(ws + 307584);     // 128*32*32 bf16
  unsigned short* imn = (unsigned short*)(ws + 373120);    // 128*64*512 bf16
  unsigned short* sn = (unsigned short*)(ws + 2470272);    // 128*32*512 bf16

  norm_convert<<<dim3(3072), dim3(256), 0, stream>>>(im, s, nim, ns, imn, sn, acc);
  gram_all<<<dim3(256), dim3(256), 0, stream>>>(imn, sn, Gim, Gs);
  attn_pair<<<dim3(32, 64), dim3(256), 0, stream>>>(imn, sn, Gim, Gs, nim, ns,
                                                    im_m, s_m, i2t, t2i);
  loss_fused<<<dim3(128), dim3(128), 0, stream>>>(gsim, i2t, t2i, acc, out);
}